// Round 2
// baseline (4744.902 us; speedup 1.0000x reference)
//
#include <hip/hip_runtime.h>

// GRUModel: 2-layer GRU (H=64), B=4096, T=512, input dim 1, fp32.
// Mapping: lane <-> hidden unit, wave <-> NB=4 batch elems, 4 waves/block,
// 256 blocks -> 1024 waves = 1 wave/SIMD on all 256 CUs.
//
// R2 changes vs R1 (which was LDS-pipe bound at ~22.5k cyc/CU/step):
//  - h-state broadcast via v_readlane (register -> SGPR), no LDS h arrays,
//    no barriers in the time loop.
//  - Layer-0 recurrent weights live in VGPRs (192/lane), j-loop fully unrolled.
//  - Layer-1 weights in LDS padded to float4 per (j,lane): one conflict-free
//    ds_read_b128 per matrix per j (16B lane stride).
//  - r,z gates packed as float2 -> v_pk_fma_f32 (fp32 packed peak).

typedef float v2f __attribute__((ext_vector_type(2)));
typedef float v4f __attribute__((ext_vector_type(4)));

#define T_LEN 512
#define NB 4

static __device__ __forceinline__ float sigm(float x) {
    return 1.0f / (1.0f + __expf(-x));
}
static __device__ __forceinline__ float tanh_fast(float x) {
    return 2.0f / (1.0f + __expf(-2.0f * x)) - 1.0f;
}
// broadcast lane j's value of v to all lanes (lands in an SGPR)
static __device__ __forceinline__ float bcast(float v, int j) {
    return __builtin_bit_cast(float, __builtin_amdgcn_readlane(__builtin_bit_cast(int, v), j));
}

__global__ __launch_bounds__(256, 1)
void gru_fused(const float* __restrict__ x,      // [B, T]
               const float* __restrict__ w_ih0,  // [192]
               const float* __restrict__ w_hh0,  // [192,64]
               const float* __restrict__ b_ih0,  // [192]
               const float* __restrict__ b_hh0,  // [192]
               const float* __restrict__ w_ih1,  // [192,64]
               const float* __restrict__ w_hh1,  // [192,64]
               const float* __restrict__ b_ih1,  // [192]
               const float* __restrict__ b_hh1,  // [192]
               const float* __restrict__ fc_w,   // [64]
               const float* __restrict__ fc_b,   // [1]
               float* __restrict__ out)          // [B]
{
    extern __shared__ float lds[];
    float* lwA = lds;           // [64 j][64 u][4]: w_ih1 r,z,n,pad for (u,j)
    float* lwB = lds + 16384;   // [64 j][64 u][4]: w_hh1 r,z,n,pad

    const int tid  = threadIdx.x;
    const int lane = tid & 63;
    const int wv   = tid >> 6;

    // ---- stage layer-1 weights, dst-major (conflict-free LDS writes) ----
    for (int d = tid; d < 16384; d += 256) {
        const int g = d & 3;
        if (g < 3) {
            const int u = (d >> 2) & 63;
            const int j = d >> 8;
            const int src = (g * 64 + u) * 64 + j;
            lwA[d] = w_ih1[src];
            lwB[d] = w_hh1[src];
        } else {
            lwA[d] = 0.f;
            lwB[d] = 0.f;
        }
    }

    // ---- layer-0 recurrent weights into registers (lane = unit) ----
    v2f   w0rz[64];  // {W_r[lane][j], W_z[lane][j]}
    float w0n[64];
    {
        const float* rowr = w_hh0 + (0 * 64 + lane) * 64;
        const float* rowz = w_hh0 + (64  + lane) * 64;
        const float* rown = w_hh0 + (128 + lane) * 64;
        #pragma unroll
        for (int j = 0; j < 64; j++) {
            v2f w; w.x = rowr[j]; w.y = rowz[j];
            w0rz[j] = w;
            w0n[j]  = rown[j];
        }
    }

    // per-lane constants
    const float wi0r = w_ih0[lane], wi0z = w_ih0[64 + lane], wi0n = w_ih0[128 + lane];
    v2f b0rz; b0rz.x = b_ih0[lane] + b_hh0[lane];
    b0rz.y = b_ih0[64 + lane] + b_hh0[64 + lane];
    const float b0in = b_ih0[128 + lane];
    const float b0hn = b_hh0[128 + lane];
    v2f b1rz; b1rz.x = b_ih1[lane] + b_hh1[lane];
    b1rz.y = b_ih1[64 + lane] + b_hh1[64 + lane];
    const float b1in = b_ih1[128 + lane];
    const float b1hn = b_hh1[128 + lane];

    __syncthreads();

    const int e0 = (blockIdx.x * 4 + wv) * NB;
    const float* xr = x + (size_t)e0 * T_LEN;

    float h0r[NB] = {0.f, 0.f, 0.f, 0.f};
    float h1r[NB] = {0.f, 0.f, 0.f, 0.f};

    float xv[NB], xn[NB];
    #pragma unroll
    for (int e = 0; e < NB; e++) xv[e] = xr[e * T_LEN];

    for (int t = 0; t < T_LEN; t++) {
        // prefetch next x (clamped index; value unused on last iter)
        const int tn = (t + 1) & (T_LEN - 1);
        #pragma unroll
        for (int e = 0; e < NB; e++) xn[e] = xr[e * T_LEN + tn];

        // ======== layer 0: W_hh0 @ h0 (weights in VGPRs, h via readlane) ====
        v2f   arz[NB];
        float an[NB];
        #pragma unroll
        for (int e = 0; e < NB; e++) { arz[e].x = 0.f; arz[e].y = 0.f; an[e] = 0.f; }
        #pragma unroll
        for (int j = 0; j < 64; j++) {
            #pragma unroll
            for (int e = 0; e < NB; e++) {
                const float h = bcast(h0r[e], j);
                v2f h2; h2.x = h; h2.y = h;
                arz[e] = __builtin_elementwise_fma(w0rz[j], h2, arz[e]);
                an[e]  = fmaf(w0n[j], h, an[e]);
            }
        }
        #pragma unroll
        for (int e = 0; e < NB; e++) {
            const float r = sigm(fmaf(xv[e], wi0r, b0rz.x) + arz[e].x);
            const float z = sigm(fmaf(xv[e], wi0z, b0rz.y) + arz[e].y);
            const float n = tanh_fast(fmaf(xv[e], wi0n, b0in) + r * (an[e] + b0hn));
            h0r[e] = n + z * (h0r[e] - n);
        }

        // ======== layer 1: W_ih1 @ h0new + W_hh1 @ h1 ========
        v2f   brz[NB], crz[NB];
        float bn[NB], cn[NB];
        #pragma unroll
        for (int e = 0; e < NB; e++) {
            brz[e].x = 0.f; brz[e].y = 0.f; bn[e] = 0.f;
            crz[e].x = 0.f; crz[e].y = 0.f; cn[e] = 0.f;
        }
        #pragma unroll 8
        for (int j = 0; j < 64; j++) {
            const v4f ih4 = *(const v4f*)(lwA + (j * 64 + lane) * 4);
            const v4f hh4 = *(const v4f*)(lwB + (j * 64 + lane) * 4);
            v2f ihrz; ihrz.x = ih4.x; ihrz.y = ih4.y;
            v2f hhrz; hhrz.x = hh4.x; hhrz.y = hh4.y;
            #pragma unroll
            for (int e = 0; e < NB; e++) {
                const float g = bcast(h0r[e], j);   // h0new[j][e]
                const float q = bcast(h1r[e], j);   // h1[j][e]
                v2f g2; g2.x = g; g2.y = g;
                v2f q2; q2.x = q; q2.y = q;
                brz[e] = __builtin_elementwise_fma(ihrz, g2, brz[e]);
                bn[e]  = fmaf(ih4.z, g, bn[e]);
                crz[e] = __builtin_elementwise_fma(hhrz, q2, crz[e]);
                cn[e]  = fmaf(hh4.z, q, cn[e]);
            }
        }
        #pragma unroll
        for (int e = 0; e < NB; e++) {
            const float r = sigm(brz[e].x + crz[e].x + b1rz.x);
            const float z = sigm(brz[e].y + crz[e].y + b1rz.y);
            const float n = tanh_fast(bn[e] + b1in + r * (cn[e] + b1hn));
            h1r[e] = n + z * (h1r[e] - n);
        }

        #pragma unroll
        for (int e = 0; e < NB; e++) xv[e] = xn[e];
    }

    // ======== final FC: out[b] = sum_i fc_w[i] * h1[b, i] + fc_b ========
    const float fw = fc_w[lane];
    const float fb = fc_b[0];
    #pragma unroll
    for (int e = 0; e < NB; e++) {
        float v = fw * h1r[e];
        #pragma unroll
        for (int off = 32; off > 0; off >>= 1)
            v += __shfl_xor(v, off, 64);
        if (lane == 0) out[e0 + e] = v + fb;
    }
}

extern "C" void kernel_launch(void* const* d_in, const int* in_sizes, int n_in,
                              void* d_out, int out_size, void* d_ws, size_t ws_size,
                              hipStream_t stream)
{
    const float* x     = (const float*)d_in[0];
    const float* w_ih0 = (const float*)d_in[1];
    const float* w_hh0 = (const float*)d_in[2];
    const float* b_ih0 = (const float*)d_in[3];
    const float* b_hh0 = (const float*)d_in[4];
    const float* w_ih1 = (const float*)d_in[5];
    const float* w_hh1 = (const float*)d_in[6];
    const float* b_ih1 = (const float*)d_in[7];
    const float* b_hh1 = (const float*)d_in[8];
    const float* fc_w  = (const float*)d_in[9];
    const float* fc_b  = (const float*)d_in[10];
    float* out = (float*)d_out;

    // 2 x [64][64][4] floats = 128 KB dynamic LDS (layer-1 weights, padded)
    const size_t shmem = (size_t)(2 * 16384) * sizeof(float);
    (void)hipFuncSetAttribute((const void*)gru_fused,
                              hipFuncAttributeMaxDynamicSharedMemorySize,
                              (int)shmem);

    hipLaunchKernelGGL(gru_fused, dim3(256), dim3(256), shmem, stream,
                       x, w_ih0, w_hh0, b_ih0, b_hh0,
                       w_ih1, w_hh1, b_ih1, b_hh1, fc_w, fc_b, out);
}

// Round 3
// 911.444 us; speedup vs baseline: 5.2059x; 5.2059x over previous
//
#include <hip/hip_runtime.h>

// GRUModel: 2-layer GRU (H=64), B=4096, T=512, fp32 in/out — MFMA version.
//
// Per CU (block of 256 = 4 waves): M=16 batch rows. Per step, each layer's
// matvec batch is one GEMM M=16 x N=192 x K=64(L0)/128(L1) on
// mfma_f32_16x16x32_bf16, split-bf16 (hi+lo) for fp32-grade precision:
// D ~= Ah*Bh + Ah*Bl + Al*Bh  (3 MFMAs per tile-chunk).
//
// N split across waves so wave w owns units u=16w..16w+15 for ALL 3 gates
// (tiles {w, 4+w, 8+w}) -> gates are lane-local in C-layout; h0/h1 state
// lives in registers (C-layout: lane q*16+n holds h[m=4q+reg][u=16w+n]).
// Weight B-fragments are loop-invariant -> precomputed in VGPRs (36 short8).
// A-fragments (h) round-trip through LDS each step, hi/lo packed per dword,
// double-buffered by t-parity; 2 __syncthreads per step.
//
// Frag layouts (m89/m120-verified):
//   A: lane holds A[m=lane&15][k=(lane>>4)*8+j], j=0..7
//   B: lane holds B[k=(lane>>4)*8+j][n=lane&15]
//   C/D: lane holds D[m=(lane>>4)*4+reg][n=lane&15]

typedef short short8 __attribute__((ext_vector_type(8)));
typedef float v4f   __attribute__((ext_vector_type(4)));
typedef int   v4i   __attribute__((ext_vector_type(4)));

#define T_LEN 512
#define HRS 68  // h-array row stride in dwords (16B-aligned, conflict-spread)

static __device__ __forceinline__ unsigned bf16rn(float f) {
    unsigned u = __builtin_bit_cast(unsigned, f);
    return (u + 0x7FFFu + ((u >> 16) & 1u)) >> 16;   // round-to-nearest-even
}
// pack fp32 -> (bf16 hi | bf16 lo<<16) in one dword
static __device__ __forceinline__ int pack_hl(float v) {
    unsigned hb = bf16rn(v);
    float hf = __builtin_bit_cast(float, hb << 16);
    unsigned lb = bf16rn(v - hf);
    return (int)(hb | (lb << 16));
}
static __device__ __forceinline__ float sigm(float x) {
    return 1.0f / (1.0f + __expf(-x));
}
static __device__ __forceinline__ float tanh_fast(float x) {
    return 2.0f / (1.0f + __expf(-2.0f * x)) - 1.0f;
}
static __device__ __forceinline__ v4f mfma16(short8 a, short8 b, v4f c) {
    return __builtin_amdgcn_mfma_f32_16x16x32_bf16(a, b, c, 0, 0, 0);
}
// read one K-chunk A-fragment (8 k's) from hi/lo-interleaved LDS array
static __device__ __forceinline__ void afrag(const int* p, short8& hi, short8& lo) {
    v4i d0 = *(const v4i*)p;
    v4i d1 = *(const v4i*)(p + 4);
    v4i h, l;
    h.x = __builtin_amdgcn_perm(d0.y, d0.x, 0x05040100);
    h.y = __builtin_amdgcn_perm(d0.w, d0.z, 0x05040100);
    h.z = __builtin_amdgcn_perm(d1.y, d1.x, 0x05040100);
    h.w = __builtin_amdgcn_perm(d1.w, d1.z, 0x05040100);
    l.x = __builtin_amdgcn_perm(d0.y, d0.x, 0x07060302);
    l.y = __builtin_amdgcn_perm(d0.w, d0.z, 0x07060302);
    l.z = __builtin_amdgcn_perm(d1.y, d1.x, 0x07060302);
    l.w = __builtin_amdgcn_perm(d1.w, d1.z, 0x07060302);
    hi = __builtin_bit_cast(short8, h);
    lo = __builtin_bit_cast(short8, l);
}

__global__ __launch_bounds__(256, 1)
void gru_mfma(const float* __restrict__ x,
              const float* __restrict__ w_ih0, const float* __restrict__ w_hh0,
              const float* __restrict__ b_ih0, const float* __restrict__ b_hh0,
              const float* __restrict__ w_ih1, const float* __restrict__ w_hh1,
              const float* __restrict__ b_ih1, const float* __restrict__ b_hh1,
              const float* __restrict__ fc_w,  const float* __restrict__ fc_b,
              float* __restrict__ out)
{
    __shared__ __align__(16) float xs[T_LEN * 17];       // x[t][m], padded
    __shared__ __align__(16) int h0b[2][16 * HRS];       // h0 hi|lo, 2 parities
    __shared__ __align__(16) int h1b[2][16 * HRS];
    __shared__ float red[64];

    const int tid  = threadIdx.x;
    const int w    = tid >> 6;      // wave id = N-split
    const int lane = tid & 63;
    const int n    = lane & 15;
    const int q    = lane >> 4;
    const int u    = w * 16 + n;    // unit owned in gate phase

    // ---- stage this block's 16 x-rows into LDS (coalesced) ----
    const float* xg = x + (size_t)(blockIdx.x * 16) * T_LEN;
    for (int i = tid; i < 16 * T_LEN; i += 256) {
        const int row = i >> 9, t = i & 511;
        xs[t * 17 + row] = xg[row * T_LEN + t];
    }
    for (int i = tid; i < 16 * HRS; i += 256) { h0b[0][i] = 0; h1b[0][i] = 0; }

    // ---- loop-invariant weight B-fragments (hi/lo) into VGPRs ----
    // rows of W accessed by this lane: u (r), 64+u (z), 128+u (n)
    short8 B0h[3][2], B0l[3][2];        // W_hh0, K=64 -> 2 chunks
    short8 B1h[3][4], B1l[3][4];        // [W_ih1 | W_hh1], K=128 -> 4 chunks
    {
        const int rows[3] = {u, 64 + u, 128 + u};
        #pragma unroll
        for (int g = 0; g < 3; g++) {
            #pragma unroll
            for (int c = 0; c < 2; c++) {
                const float* r0 = w_hh0 + rows[g] * 64 + 32 * c + 8 * q;
                #pragma unroll
                for (int j = 0; j < 8; j++) {
                    float v = r0[j];
                    unsigned hb = bf16rn(v);
                    float hf = __builtin_bit_cast(float, hb << 16);
                    B0h[g][c][j] = (short)hb;
                    B0l[g][c][j] = (short)bf16rn(v - hf);
                }
            }
            #pragma unroll
            for (int c = 0; c < 4; c++) {
                const float* M = (c < 2) ? w_ih1 : w_hh1;
                const float* r0 = M + rows[g] * 64 + 32 * (c & 1) + 8 * q;
                #pragma unroll
                for (int j = 0; j < 8; j++) {
                    float v = r0[j];
                    unsigned hb = bf16rn(v);
                    float hf = __builtin_bit_cast(float, hb << 16);
                    B1h[g][c][j] = (short)hb;
                    B1l[g][c][j] = (short)bf16rn(v - hf);
                }
            }
        }
    }

    // per-lane gate constants (for unit u)
    const float wir = w_ih0[u], wiz = w_ih0[64 + u], win = w_ih0[128 + u];
    const float br0 = b_ih0[u] + b_hh0[u];
    const float bz0 = b_ih0[64 + u] + b_hh0[64 + u];
    const float bin0 = b_ih0[128 + u], bhn0 = b_hh0[128 + u];
    const float br1 = b_ih1[u] + b_hh1[u];
    const float bz1 = b_ih1[64 + u] + b_hh1[64 + u];
    const float bin1 = b_ih1[128 + u], bhn1 = b_hh1[128 + u];

    float h0st[4] = {0.f, 0.f, 0.f, 0.f};   // h0[m=4q+reg][u]
    float h1st[4] = {0.f, 0.f, 0.f, 0.f};   // h1[m=4q+reg][u]

    __syncthreads();

    // A-frag read base for this lane (m = lane&15 = n): chunk c at +32c
    const int abase = n * HRS + 8 * q;

    #pragma unroll 1
    for (int t = 0; t < T_LEN; t++) {
        const int pr = t & 1, pw = pr ^ 1;

        float xv[4];
        #pragma unroll
        for (int r = 0; r < 4; r++) xv[r] = xs[t * 17 + 4 * q + r];

        // ======== layer 0: G0 = h0 @ W_hh0^T (+ x-rank1 + biases) ========
        short8 a0h[2], a0l[2];
        afrag(&h0b[pr][abase +  0], a0h[0], a0l[0]);
        afrag(&h0b[pr][abase + 32], a0h[1], a0l[1]);

        v4f accR, accZ, accN;
        #pragma unroll
        for (int r = 0; r < 4; r++) {
            accR[r] = fmaf(xv[r], wir, br0);
            accZ[r] = fmaf(xv[r], wiz, bz0);
            accN[r] = 0.f;
        }
        #pragma unroll
        for (int c = 0; c < 2; c++) {
            accR = mfma16(a0h[c], B0h[0][c], accR);
            accZ = mfma16(a0h[c], B0h[1][c], accZ);
            accN = mfma16(a0h[c], B0h[2][c], accN);
            accR = mfma16(a0h[c], B0l[0][c], accR);
            accZ = mfma16(a0h[c], B0l[1][c], accZ);
            accN = mfma16(a0h[c], B0l[2][c], accN);
            accR = mfma16(a0l[c], B0h[0][c], accR);
            accZ = mfma16(a0l[c], B0h[1][c], accZ);
            accN = mfma16(a0l[c], B0h[2][c], accN);
        }
        #pragma unroll
        for (int r = 0; r < 4; r++) {
            const float rg = sigm(accR[r]);
            const float zg = sigm(accZ[r]);
            const float inn = fmaf(xv[r], win, bin0);
            const float ng = tanh_fast(inn + rg * (accN[r] + bhn0));
            h0st[r] = ng + zg * (h0st[r] - ng);
            h0b[pw][(4 * q + r) * HRS + u] = pack_hl(h0st[r]);
        }
        __syncthreads();   // h0new visible to all waves

        // ======== layer 1: G1 = [h0new | h1] @ [W_ih1 ; W_hh1]^T ========
        short8 g0h[2], g0l[2], g1h[2], g1l[2];
        afrag(&h0b[pw][abase +  0], g0h[0], g0l[0]);
        afrag(&h0b[pw][abase + 32], g0h[1], g0l[1]);
        afrag(&h1b[pr][abase +  0], g1h[0], g1l[0]);
        afrag(&h1b[pr][abase + 32], g1h[1], g1l[1]);

        v4f aR, aZ, aNi, aNh;
        #pragma unroll
        for (int r = 0; r < 4; r++) { aR[r] = br1; aZ[r] = bz1; aNi[r] = bin1; aNh[r] = bhn1; }

        #pragma unroll
        for (int c = 0; c < 2; c++) {   // i-side: A = h0new, B = W_ih1
            aR  = mfma16(g0h[c], B1h[0][c], aR);
            aZ  = mfma16(g0h[c], B1h[1][c], aZ);
            aNi = mfma16(g0h[c], B1h[2][c], aNi);
            aR  = mfma16(g0h[c], B1l[0][c], aR);
            aZ  = mfma16(g0h[c], B1l[1][c], aZ);
            aNi = mfma16(g0h[c], B1l[2][c], aNi);
            aR  = mfma16(g0l[c], B1h[0][c], aR);
            aZ  = mfma16(g0l[c], B1h[1][c], aZ);
            aNi = mfma16(g0l[c], B1h[2][c], aNi);
        }
        #pragma unroll
        for (int c = 0; c < 2; c++) {   // h-side: A = h1, B = W_hh1
            aR  = mfma16(g1h[c], B1h[0][c + 2], aR);
            aZ  = mfma16(g1h[c], B1h[1][c + 2], aZ);
            aNh = mfma16(g1h[c], B1h[2][c + 2], aNh);
            aR  = mfma16(g1h[c], B1l[0][c + 2], aR);
            aZ  = mfma16(g1h[c], B1l[1][c + 2], aZ);
            aNh = mfma16(g1h[c], B1l[2][c + 2], aNh);
            aR  = mfma16(g1l[c], B1h[0][c + 2], aR);
            aZ  = mfma16(g1l[c], B1h[1][c + 2], aZ);
            aNh = mfma16(g1l[c], B1h[2][c + 2], aNh);
        }
        #pragma unroll
        for (int r = 0; r < 4; r++) {
            const float rg = sigm(aR[r]);
            const float zg = sigm(aZ[r]);
            const float ng = tanh_fast(aNi[r] + rg * aNh[r]);
            h1st[r] = ng + zg * (h1st[r] - ng);
            h1b[pw][(4 * q + r) * HRS + u] = pack_hl(h1st[r]);
        }
        __syncthreads();   // h1new visible before next step
    }

    // ======== FC epilogue: out[m] = sum_u fc_w[u] h1[m][u] + fc_b ========
    const float fw = fc_w[u];
    #pragma unroll
    for (int r = 0; r < 4; r++) {
        float v = fw * h1st[r];
        v += __shfl_xor(v, 1, 64);
        v += __shfl_xor(v, 2, 64);
        v += __shfl_xor(v, 4, 64);
        v += __shfl_xor(v, 8, 64);     // sum over 16 n-lanes (q preserved)
        if (n == 0) red[(4 * q + r) * 4 + w] = v;
    }
    __syncthreads();
    if (tid < 16) {
        const float s = red[tid * 4] + red[tid * 4 + 1] + red[tid * 4 + 2] + red[tid * 4 + 3];
        out[blockIdx.x * 16 + tid] = s + fc_b[0];
    }
}

extern "C" void kernel_launch(void* const* d_in, const int* in_sizes, int n_in,
                              void* d_out, int out_size, void* d_ws, size_t ws_size,
                              hipStream_t stream)
{
    const float* x     = (const float*)d_in[0];
    const float* w_ih0 = (const float*)d_in[1];
    const float* w_hh0 = (const float*)d_in[2];
    const float* b_ih0 = (const float*)d_in[3];
    const float* b_hh0 = (const float*)d_in[4];
    const float* w_ih1 = (const float*)d_in[5];
    const float* w_hh1 = (const float*)d_in[6];
    const float* b_ih1 = (const float*)d_in[7];
    const float* b_hh1 = (const float*)d_in[8];
    const float* fc_w  = (const float*)d_in[9];
    const float* fc_b  = (const float*)d_in[10];
    float* out = (float*)d_out;

    hipLaunchKernelGGL(gru_mfma, dim3(256), dim3(256), 0, stream,
                       x, w_ih0, w_hh0, b_ih0, b_hh0,
                       w_ih1, w_hh1, b_ih1, b_hh1, fc_w, fc_b, out);
}

// Round 4
// 840.517 us; speedup vs baseline: 5.6452x; 1.0844x over previous
//
#include <hip/hip_runtime.h>

// GRUModel: 2-layer GRU (H=64), B=4096, T=512, fp32 in/out — MFMA round 4.
//
// Per CU (block of 256 = 4 waves): M=16 batch rows, N=192 split across waves
// (wave w owns units u=16w..16w+15 for all 3 gates -> gates lane-local in
// C-layout; h-state fp32 in registers, never quantized in place).
//
// R4 changes vs R3 (911 us, MfmaUtil 21%, ~1.8k cyc/step unexplained stall):
//  - split-fp16 2-product instead of split-bf16 3-product:
//      D = (Ah + Al) @ Bh,  Ah=fp16(h), Al=fp16(h-Ah)  (~22-bit A mantissa),
//      weights single fp16 (static systematic 2^-11 -> ~1e-4 final).
//      36 MFMAs/step instead of 54.
//  - planar fp16 LDS h-planes (hi,lo separate, [m][k] stride 72): A-frag is
//    ONE ds_read_b128, zero v_perm unpacking.
//  - ONE barrier/step: [L0 ; write h0 ; BARRIER ; L1 i+h ; write h1] is
//    race-free under parity double-buffering (every writer/reader pair of the
//    same parity buffer is separated by exactly one barrier).
//
// Frag layouts (m89/m120-verified, dtype-independent):
//   A: lane holds A[m=lane&15][k=(lane>>4)*8+j], j=0..7
//   B: lane holds B[k=(lane>>4)*8+j][n=lane&15]
//   C/D: lane holds D[m=(lane>>4)*4+reg][n=lane&15]

typedef _Float16 half8 __attribute__((ext_vector_type(8)));
typedef float    v4f   __attribute__((ext_vector_type(4)));

#define T_LEN 512
#define KS 72   // fp16-element row stride of h planes (16B-aligned reads)

static __device__ __forceinline__ float sigm(float x) {
    return 1.0f / (1.0f + __expf(-x));
}
static __device__ __forceinline__ float tanh_fast(float x) {
    return 2.0f / (1.0f + __expf(-2.0f * x)) - 1.0f;
}
static __device__ __forceinline__ v4f mfma16(half8 a, half8 b, v4f c) {
    return __builtin_amdgcn_mfma_f32_16x16x32_f16(a, b, c, 0, 0, 0);
}
static __device__ __forceinline__ half8 ld8(const _Float16* p) {
    return *(const half8*)p;
}

__global__ __launch_bounds__(256, 1)
void gru_mfma(const float* __restrict__ x,
              const float* __restrict__ w_ih0, const float* __restrict__ w_hh0,
              const float* __restrict__ b_ih0, const float* __restrict__ b_hh0,
              const float* __restrict__ w_ih1, const float* __restrict__ w_hh1,
              const float* __restrict__ b_ih1, const float* __restrict__ b_hh1,
              const float* __restrict__ fc_w,  const float* __restrict__ fc_b,
              float* __restrict__ out)
{
    __shared__ __align__(16) float xs[T_LEN * 17];            // x[t][m], padded
    __shared__ __align__(16) _Float16 h0hi[2][16 * KS];       // h0 planes, 2 parities
    __shared__ __align__(16) _Float16 h0lo[2][16 * KS];
    __shared__ __align__(16) _Float16 h1hi[2][16 * KS];
    __shared__ __align__(16) _Float16 h1lo[2][16 * KS];
    __shared__ float red[64];

    const int tid  = threadIdx.x;
    const int w    = tid >> 6;      // wave id = N-split
    const int lane = tid & 63;
    const int n    = lane & 15;
    const int q    = lane >> 4;
    const int u    = w * 16 + n;    // unit owned in gate phase

    // ---- stage this block's 16 x-rows into LDS (coalesced) ----
    const float* xg = x + (size_t)(blockIdx.x * 16) * T_LEN;
    for (int i = tid; i < 16 * T_LEN; i += 256) {
        const int row = i >> 9, t = i & 511;
        xs[t * 17 + row] = xg[row * T_LEN + t];
    }
    for (int i = tid; i < 16 * KS; i += 256) {
        h0hi[0][i] = (_Float16)0; h0lo[0][i] = (_Float16)0;
        h1hi[0][i] = (_Float16)0; h1lo[0][i] = (_Float16)0;
    }

    // ---- loop-invariant weight B-fragments (single fp16) into VGPRs ----
    // rows of W accessed by this lane: u (r), 64+u (z), 128+u (n)
    half8 B0[3][2];   // W_hh0, K=64 -> 2 chunks
    half8 B1[3][4];   // [W_ih1 (c=0,1) | W_hh1 (c=2,3)], K=128 -> 4 chunks
    {
        const int rows[3] = {u, 64 + u, 128 + u};
        #pragma unroll
        for (int g = 0; g < 3; g++) {
            #pragma unroll
            for (int c = 0; c < 2; c++) {
                const float* r0 = w_hh0 + rows[g] * 64 + 32 * c + 8 * q;
                #pragma unroll
                for (int j = 0; j < 8; j++) B0[g][c][j] = (_Float16)r0[j];
            }
            #pragma unroll
            for (int c = 0; c < 4; c++) {
                const float* M = (c < 2) ? w_ih1 : w_hh1;
                const float* r0 = M + rows[g] * 64 + 32 * (c & 1) + 8 * q;
                #pragma unroll
                for (int j = 0; j < 8; j++) B1[g][c][j] = (_Float16)r0[j];
            }
        }
    }

    // per-lane gate constants (for unit u)
    const float wir = w_ih0[u], wiz = w_ih0[64 + u], win = w_ih0[128 + u];
    const float br0 = b_ih0[u] + b_hh0[u];
    const float bz0 = b_ih0[64 + u] + b_hh0[64 + u];
    const float bin0 = b_ih0[128 + u], bhn0 = b_hh0[128 + u];
    const float br1 = b_ih1[u] + b_hh1[u];
    const float bz1 = b_ih1[64 + u] + b_hh1[64 + u];
    const float bin1 = b_ih1[128 + u], bhn1 = b_hh1[128 + u];

    float h0st[4] = {0.f, 0.f, 0.f, 0.f};   // fp32 h0[m=4q+reg][u] (authoritative)
    float h1st[4] = {0.f, 0.f, 0.f, 0.f};

    __syncthreads();

    const int abase = n * KS + 8 * q;       // A-frag base (fp16 elems)
    const int wbase = u;                    // write column

    #pragma unroll 2
    for (int t = 0; t < T_LEN; t++) {
        const int pr = t & 1, pw = pr ^ 1;

        // ---- A-frags of h0[t-1] (parity pr; written pre-B@t-1, we are
        //      post-B@t-1 -> safe) ----
        const half8 a0h0 = ld8(&h0hi[pr][abase]);
        const half8 a0h1 = ld8(&h0hi[pr][abase + 32]);
        const half8 a0l0 = ld8(&h0lo[pr][abase]);
        const half8 a0l1 = ld8(&h0lo[pr][abase + 32]);

        float xv[4];
        #pragma unroll
        for (int r = 0; r < 4; r++) xv[r] = xs[t * 17 + 4 * q + r];

        // ======== layer 0: G0 = (h0hi+h0lo) @ W_hh0^T + x-rank1 + biases ====
        v4f accR, accZ, accN;
        #pragma unroll
        for (int r = 0; r < 4; r++) {
            accR[r] = fmaf(xv[r], wir, br0);
            accZ[r] = fmaf(xv[r], wiz, bz0);
            accN[r] = 0.f;
        }
        accR = mfma16(a0h0, B0[0][0], accR);
        accZ = mfma16(a0h0, B0[1][0], accZ);
        accN = mfma16(a0h0, B0[2][0], accN);
        accR = mfma16(a0h1, B0[0][1], accR);
        accZ = mfma16(a0h1, B0[1][1], accZ);
        accN = mfma16(a0h1, B0[2][1], accN);
        accR = mfma16(a0l0, B0[0][0], accR);
        accZ = mfma16(a0l0, B0[1][0], accZ);
        accN = mfma16(a0l0, B0[2][0], accN);
        accR = mfma16(a0l1, B0[0][1], accR);
        accZ = mfma16(a0l1, B0[1][1], accZ);
        accN = mfma16(a0l1, B0[2][1], accN);

        #pragma unroll
        for (int r = 0; r < 4; r++) {
            const float rg = sigm(accR[r]);
            const float zg = sigm(accZ[r]);
            const float inn = fmaf(xv[r], win, bin0);
            const float ng = tanh_fast(inn + rg * (accN[r] + bhn0));
            const float h = ng + zg * (h0st[r] - ng);
            h0st[r] = h;
            const _Float16 ah = (_Float16)h;
            const _Float16 al = (_Float16)(h - (float)ah);
            h0hi[pw][(4 * q + r) * KS + wbase] = ah;
            h0lo[pw][(4 * q + r) * KS + wbase] = al;
        }

        __syncthreads();   // the ONE barrier: h0new visible; also orders h1[t-1]

        // ======== layer 1: G1 = [h0new | h1] @ [W_ih1 ; W_hh1]^T ========
        const half8 g0h0 = ld8(&h0hi[pw][abase]);
        const half8 g0h1 = ld8(&h0hi[pw][abase + 32]);
        const half8 g0l0 = ld8(&h0lo[pw][abase]);
        const half8 g0l1 = ld8(&h0lo[pw][abase + 32]);
        const half8 g1h0 = ld8(&h1hi[pr][abase]);
        const half8 g1h1 = ld8(&h1hi[pr][abase + 32]);
        const half8 g1l0 = ld8(&h1lo[pr][abase]);
        const half8 g1l1 = ld8(&h1lo[pr][abase + 32]);

        v4f aRi, aZi, aNi, aRh, aZh, aNh;
        #pragma unroll
        for (int r = 0; r < 4; r++) {
            aRi[r] = br1;  aZi[r] = bz1;  aNi[r] = bin1;
            aRh[r] = 0.f;  aZh[r] = 0.f;  aNh[r] = bhn1;
        }
        // 6 independent chains of depth 4 (i-side uses h0new, h-side uses h1)
        aRi = mfma16(g0h0, B1[0][0], aRi);
        aZi = mfma16(g0h0, B1[1][0], aZi);
        aNi = mfma16(g0h0, B1[2][0], aNi);
        aRh = mfma16(g1h0, B1[0][2], aRh);
        aZh = mfma16(g1h0, B1[1][2], aZh);
        aNh = mfma16(g1h0, B1[2][2], aNh);
        aRi = mfma16(g0h1, B1[0][1], aRi);
        aZi = mfma16(g0h1, B1[1][1], aZi);
        aNi = mfma16(g0h1, B1[2][1], aNi);
        aRh = mfma16(g1h1, B1[0][3], aRh);
        aZh = mfma16(g1h1, B1[1][3], aZh);
        aNh = mfma16(g1h1, B1[2][3], aNh);
        aRi = mfma16(g0l0, B1[0][0], aRi);
        aZi = mfma16(g0l0, B1[1][0], aZi);
        aNi = mfma16(g0l0, B1[2][0], aNi);
        aRh = mfma16(g1l0, B1[0][2], aRh);
        aZh = mfma16(g1l0, B1[1][2], aZh);
        aNh = mfma16(g1l0, B1[2][2], aNh);
        aRi = mfma16(g0l1, B1[0][1], aRi);
        aZi = mfma16(g0l1, B1[1][1], aZi);
        aNi = mfma16(g0l1, B1[2][1], aNi);
        aRh = mfma16(g1l1, B1[0][3], aRh);
        aZh = mfma16(g1l1, B1[1][3], aZh);
        aNh = mfma16(g1l1, B1[2][3], aNh);

        #pragma unroll
        for (int r = 0; r < 4; r++) {
            const float rg = sigm(aRi[r] + aRh[r]);
            const float zg = sigm(aZi[r] + aZh[r]);
            const float ng = tanh_fast(aNi[r] + rg * aNh[r]);
            const float h = ng + zg * (h1st[r] - ng);
            h1st[r] = h;
            const _Float16 ah = (_Float16)h;
            const _Float16 al = (_Float16)(h - (float)ah);
            h1hi[pw][(4 * q + r) * KS + wbase] = ah;
            h1lo[pw][(4 * q + r) * KS + wbase] = al;
        }
        // no second barrier: next step's h1 readers sit behind BARRIER@t+1
    }

    // ======== FC epilogue: out[m] = sum_u fc_w[u] h1[m][u] + fc_b ========
    const float fw = fc_w[u];
    #pragma unroll
    for (int r = 0; r < 4; r++) {
        float v = fw * h1st[r];
        v += __shfl_xor(v, 1, 64);
        v += __shfl_xor(v, 2, 64);
        v += __shfl_xor(v, 4, 64);
        v += __shfl_xor(v, 8, 64);     // sum over 16 n-lanes (q preserved)
        if (n == 0) red[(4 * q + r) * 4 + w] = v;
    }
    __syncthreads();
    if (tid < 16) {
        const float s = red[tid * 4] + red[tid * 4 + 1] + red[tid * 4 + 2] + red[tid * 4 + 3];
        out[blockIdx.x * 16 + tid] = s + fc_b[0];
    }
}

extern "C" void kernel_launch(void* const* d_in, const int* in_sizes, int n_in,
                              void* d_out, int out_size, void* d_ws, size_t ws_size,
                              hipStream_t stream)
{
    const float* x     = (const float*)d_in[0];
    const float* w_ih0 = (const float*)d_in[1];
    const float* w_hh0 = (const float*)d_in[2];
    const float* b_ih0 = (const float*)d_in[3];
    const float* b_hh0 = (const float*)d_in[4];
    const float* w_ih1 = (const float*)d_in[5];
    const float* w_hh1 = (const float*)d_in[6];
    const float* b_ih1 = (const float*)d_in[7];
    const float* b_hh1 = (const float*)d_in[8];
    const float* fc_w  = (const float*)d_in[9];
    const float* fc_b  = (const float*)d_in[10];
    float* out = (float*)d_out;

    hipLaunchKernelGGL(gru_mfma, dim3(256), dim3(256), 0, stream,
                       x, w_ih0, w_hh0, b_ih0, b_hh0,
                       w_ih1, w_hh1, b_ih1, b_hh1, fc_w, fc_b, out);
}